// Round 3
// baseline (379.799 us; speedup 1.0000x reference)
//
#include <hip/hip_runtime.h>
#include <math.h>

// CapsuleRouting: u (8,144,16,16,12,12) f32, a (8,144,12,12) f32
// out: v (8,16,16,144) f32 ++ a_out (8,16,144) f32
//
// r_i = a/C + u.(sum of past v)  =>  3 streaming passes over u, no r.
// This version: NO atomics, NO barriers, NO LDS in the streaming pass.
//  - thread = (c, pos-quad): all u/V/a accesses are float4
//  - softmax over C via __shfl_xor (c = lane bits 2-5)
//  - per-block partial sums -> s_red reduction kernel -> q squash kernel
//  - a_out = sn/(1+sn) analytically; V set (not +=) at iter0 => no memsets

#define NB 8
#define BDIM 144
#define CDIM 16
#define PDIM 16
#define SDIM 144
#define BC 8
#define NBC (BDIM / BC)  // 18 chunks
#define NPT 9            // pos tiles of 16
#define VELEMS (NB * CDIM * PDIM * SDIM)  // 294912
#define AELEMS (NB * CDIM * SDIM)         // 18432
#define USTRIDE (CDIM * PDIM * SDIM)      // 36864 floats between B's

__device__ __forceinline__ float4 ld4(const float* p) { return *(const float4*)p; }
__device__ __forceinline__ void st4(float* p, float4 v) { *(float4*)p = v; }

// iter 0: uniform weights 1/16 — pure streaming partial sum
__global__ __launch_bounds__(64) void s_pass0(const float* __restrict__ u,
                                              float* __restrict__ s_part) {
  const int tid = threadIdx.x;
  const int posq = tid & 3;
  const int c = tid >> 2;
  const int b = blockIdx.z;
  const int pos0 = blockIdx.y * 16 + posq * 4;
  const float* ubase =
      u + (size_t)((b * BDIM + blockIdx.x * BC) * CDIM + c) * (PDIM * SDIM) + pos0;

  float4 sacc[PDIM];
#pragma unroll
  for (int p = 0; p < PDIM; ++p) sacc[p] = make_float4(0.f, 0.f, 0.f, 0.f);

#pragma unroll 1
  for (int j = 0; j < BC; ++j) {
    const float* ub = ubase + (size_t)j * USTRIDE;
#pragma unroll
    for (int p = 0; p < PDIM; ++p) {
      const float4 uv = ld4(ub + p * SDIM);
      sacc[p].x += uv.x; sacc[p].y += uv.y; sacc[p].z += uv.z; sacc[p].w += uv.w;
    }
  }
  float* sp = s_part + (size_t)blockIdx.x * VELEMS +
              (size_t)((b * CDIM + c) * PDIM) * SDIM + pos0;
#pragma unroll
  for (int p = 0; p < PDIM; ++p) {
    float4 o;
    o.x = sacc[p].x * 0.0625f; o.y = sacc[p].y * 0.0625f;
    o.z = sacc[p].z * 0.0625f; o.w = sacc[p].w * 0.0625f;
    st4(sp + p * SDIM, o);
  }
}

// iters 1,2: logit = a/16 + u.V ; softmax over c via shfl_xor; partial sums
__global__ __launch_bounds__(64) void s_pass(const float* __restrict__ u,
                                             const float* __restrict__ a,
                                             const float* __restrict__ V,
                                             float* __restrict__ s_part) {
  const int tid = threadIdx.x;
  const int posq = tid & 3;   // lane bits 0-1: 4 quads = 16 pos, contiguous 64B
  const int c = tid >> 2;     // lane bits 2-5: softmax partners in-wave
  const int b = blockIdx.z;
  const int pos0 = blockIdx.y * 16 + posq * 4;
  const int B0 = blockIdx.x * BC;
  const float* ubase =
      u + (size_t)((b * BDIM + B0) * CDIM + c) * (PDIM * SDIM) + pos0;

  float4 Vt[PDIM];
  {
    const float* vb = V + (size_t)((b * CDIM + c) * PDIM) * SDIM + pos0;
#pragma unroll
    for (int p = 0; p < PDIM; ++p) Vt[p] = ld4(vb + p * SDIM);
  }

  float4 sacc[PDIM];
#pragma unroll
  for (int p = 0; p < PDIM; ++p) sacc[p] = make_float4(0.f, 0.f, 0.f, 0.f);

#pragma unroll 1
  for (int j = 0; j < BC; ++j) {
    const float* ub = ubase + (size_t)j * USTRIDE;
    float4 uv[PDIM];
#pragma unroll
    for (int p = 0; p < PDIM; ++p) uv[p] = ld4(ub + p * SDIM);

    float4 dotv = make_float4(0.f, 0.f, 0.f, 0.f);
#pragma unroll
    for (int p = 0; p < PDIM; ++p) {
      dotv.x += uv[p].x * Vt[p].x; dotv.y += uv[p].y * Vt[p].y;
      dotv.z += uv[p].z * Vt[p].z; dotv.w += uv[p].w * Vt[p].w;
    }
    const float4 a4 = ld4(a + (size_t)(b * BDIM + B0 + j) * SDIM + pos0);
    float4 e;  // no-max softmax: logits O(10), fp32-safe (validated R1/R2)
    e.x = __expf(a4.x * 0.0625f + dotv.x);
    e.y = __expf(a4.y * 0.0625f + dotv.y);
    e.z = __expf(a4.z * 0.0625f + dotv.z);
    e.w = __expf(a4.w * 0.0625f + dotv.w);
    float4 ssum = e;
#pragma unroll
    for (int m = 4; m <= 32; m <<= 1) {  // reduce over c (lane bits 2-5)
      ssum.x += __shfl_xor(ssum.x, m);
      ssum.y += __shfl_xor(ssum.y, m);
      ssum.z += __shfl_xor(ssum.z, m);
      ssum.w += __shfl_xor(ssum.w, m);
    }
    float4 w;
    w.x = e.x * __builtin_amdgcn_rcpf(ssum.x);
    w.y = e.y * __builtin_amdgcn_rcpf(ssum.y);
    w.z = e.z * __builtin_amdgcn_rcpf(ssum.z);
    w.w = e.w * __builtin_amdgcn_rcpf(ssum.w);
#pragma unroll
    for (int p = 0; p < PDIM; ++p) {
      sacc[p].x += w.x * uv[p].x; sacc[p].y += w.y * uv[p].y;
      sacc[p].z += w.z * uv[p].z; sacc[p].w += w.w * uv[p].w;
    }
  }

  float* sp = s_part + (size_t)blockIdx.x * VELEMS +
              (size_t)((b * CDIM + c) * PDIM) * SDIM + pos0;
#pragma unroll
  for (int p = 0; p < PDIM; ++p) st4(sp + p * SDIM, sacc[p]);
}

// reduce 18 partial chunks -> s_red  (288 blocks x 256, fully coalesced)
__global__ __launch_bounds__(256) void s_red_k(const float* __restrict__ s_part,
                                               float* __restrict__ s_red) {
  const int gid = blockIdx.x * 256 + threadIdx.x;  // over VELEMS/4
  const float4* sp = (const float4*)s_part;
  float4 acc = sp[gid];
#pragma unroll 1
  for (int ch = 1; ch < NBC; ++ch) {
    const float4 x = sp[(size_t)ch * (VELEMS / 4) + gid];
    acc.x += x.x; acc.y += x.y; acc.z += x.z; acc.w += x.w;
  }
  ((float4*)s_red)[gid] = acc;
}

// squash + V update / final outputs.  a_out = sn/(1+sn) analytically.
__global__ __launch_bounds__(64) void q_kernel(const float* __restrict__ s_red,
                                               float* __restrict__ V,
                                               float* __restrict__ out_v,
                                               float* __restrict__ out_a,
                                               int iter) {
  const int gid = blockIdx.x * 64 + threadIdx.x;  // over AELEMS/4 = 4608
  const int posq = gid % (SDIM / 4);
  const int rem = gid / (SDIM / 4);
  const int c = rem & 15;
  const int b = rem >> 4;
  const int pos0 = posq * 4;
  const size_t base = (size_t)((b * CDIM + c) * PDIM) * SDIM + pos0;

  float4 sv[PDIM];
  float4 sn = make_float4(0.f, 0.f, 0.f, 0.f);
#pragma unroll
  for (int p = 0; p < PDIM; ++p) {
    sv[p] = ld4(s_red + base + p * SDIM);
    sn.x += sv[p].x * sv[p].x; sn.y += sv[p].y * sv[p].y;
    sn.z += sv[p].z * sv[p].z; sn.w += sv[p].w * sv[p].w;
  }
  float4 g;  // sn/(1+sn)
  g.x = sn.x * __builtin_amdgcn_rcpf(1.f + sn.x);
  g.y = sn.y * __builtin_amdgcn_rcpf(1.f + sn.y);
  g.z = sn.z * __builtin_amdgcn_rcpf(1.f + sn.z);
  g.w = sn.w * __builtin_amdgcn_rcpf(1.f + sn.w);
  float4 sc;  // g / sqrt(sn)
  sc.x = g.x * rsqrtf(sn.x); sc.y = g.y * rsqrtf(sn.y);
  sc.z = g.z * rsqrtf(sn.z); sc.w = g.w * rsqrtf(sn.w);

  if (iter < 2) {
#pragma unroll
    for (int p = 0; p < PDIM; ++p) {
      float4 nv;
      nv.x = sv[p].x * sc.x; nv.y = sv[p].y * sc.y;
      nv.z = sv[p].z * sc.z; nv.w = sv[p].w * sc.w;
      if (iter == 0) {
        st4(V + base + p * SDIM, nv);  // V = v0 (overwrites poison, no memset)
      } else {
        float4 ov = ld4(V + base + p * SDIM);
        ov.x += nv.x; ov.y += nv.y; ov.z += nv.z; ov.w += nv.w;
        st4(V + base + p * SDIM, ov);
      }
    }
  } else {
#pragma unroll
    for (int p = 0; p < PDIM; ++p) {
      float4 nv;
      nv.x = sv[p].x * sc.x; nv.y = sv[p].y * sc.y;
      nv.z = sv[p].z * sc.z; nv.w = sv[p].w * sc.w;
      st4(out_v + base + p * SDIM, nv);
    }
    st4(out_a + (size_t)(b * CDIM + c) * SDIM + pos0, g);  // ||v|| = sn/(1+sn)
  }
}

extern "C" void kernel_launch(void* const* d_in, const int* in_sizes, int n_in,
                              void* d_out, int out_size, void* d_ws, size_t ws_size,
                              hipStream_t stream) {
  const float* u = (const float*)d_in[0];
  const float* a = (const float*)d_in[1];
  float* V = (float*)d_ws;             // 1.18 MB
  float* s_red = V + VELEMS;           // 1.18 MB
  float* s_part = s_red + VELEMS;      // 18 x 1.18 MB = 21.2 MB
  float* out_v = (float*)d_out;
  float* out_a = out_v + VELEMS;

  const dim3 gS(NBC, NPT, NB);  // 18 x 9 x 8 = 1296 blocks of 64
  const int gR = VELEMS / 4 / 256;  // 288
  const int gQ = AELEMS / 4 / 64;   // 72

  s_pass0<<<gS, 64, 0, stream>>>(u, s_part);
  s_red_k<<<gR, 256, 0, stream>>>(s_part, s_red);
  q_kernel<<<gQ, 64, 0, stream>>>(s_red, V, out_v, out_a, 0);

  s_pass<<<gS, 64, 0, stream>>>(u, a, V, s_part);
  s_red_k<<<gR, 256, 0, stream>>>(s_part, s_red);
  q_kernel<<<gQ, 64, 0, stream>>>(s_red, V, out_v, out_a, 1);

  s_pass<<<gS, 64, 0, stream>>>(u, a, V, s_part);
  s_red_k<<<gR, 256, 0, stream>>>(s_part, s_red);
  q_kernel<<<gQ, 64, 0, stream>>>(s_red, V, out_v, out_a, 2);
}